// Round 2
// baseline (384.474 us; speedup 1.0000x reference)
//
#include <hip/hip_runtime.h>
#include <hip/hip_bf16.h>
#include <stdint.h>
#include <stddef.h>

#define T_SEQ 2048
#define DMODEL 2048
#define NHEADS 32
#define NKV 8
#define HD 64
#define NQD (NHEADS * HD)        // 2048
#define NKVD (NKV * HD)          // 512
#define QKVN (NQD + 2 * NKVD)    // 3072

typedef __bf16 bf16_t;
typedef __bf16 bf16x8 __attribute__((ext_vector_type(8)));
typedef __bf16 bf16x4 __attribute__((ext_vector_type(4)));
typedef __bf16 bf16x2 __attribute__((ext_vector_type(2)));
typedef float f32x4 __attribute__((ext_vector_type(4)));

typedef __attribute__((address_space(1))) void gvoid_t;
typedef __attribute__((address_space(3))) void lvoid_t;

__device__ __forceinline__ void gload_lds16(const void* g, void* l) {
  __builtin_amdgcn_global_load_lds((gvoid_t*)g, (lvoid_t*)l, 16, 0, 0);
}

// ---------------- elementwise cast f32 -> bf16 (8 elems/thread) ----------------
__global__ __launch_bounds__(256) void cast_f32_bf16_kernel(
    const float* __restrict__ in, bf16_t* __restrict__ out, int n8) {
  int i = blockIdx.x * 256 + threadIdx.x;
  if (i >= n8) return;
  const float4* p = (const float4*)in + (size_t)i * 2;
  float4 a = p[0], b = p[1];
  bf16x8 o = {(bf16_t)a.x, (bf16_t)a.y, (bf16_t)a.z, (bf16_t)a.w,
              (bf16_t)b.x, (bf16_t)b.y, (bf16_t)b.z, (bf16_t)b.w};
  *(bf16x8*)(out + (size_t)i * 8) = o;
}

// ---------------- tiled transpose + cast: out[c][r] = (bf16) in[r][c] ----------------
__global__ __launch_bounds__(256) void transpose_cast_kernel(
    const float* __restrict__ in, bf16_t* __restrict__ out,
    int R, int C, int ldin, int ldout) {
  __shared__ float tile[32][33];
  const int c0 = blockIdx.x * 32, r0 = blockIdx.y * 32;
  const int tx = threadIdx.x & 31, ty = threadIdx.x >> 5;
#pragma unroll
  for (int i = 0; i < 32; i += 8)
    tile[ty + i][tx] = in[(size_t)(r0 + ty + i) * ldin + c0 + tx];
  __syncthreads();
#pragma unroll
  for (int i = 0; i < 32; i += 8)
    out[(size_t)(c0 + ty + i) * ldout + r0 + tx] = (bf16_t)tile[tx][ty + i];
}

// ---------------- RoPE + cast ----------------
__global__ __launch_bounds__(256) void rope_cast_kernel(
    const float* __restrict__ src, const float* __restrict__ fc,
    bf16_t* __restrict__ dst, int H, int ldin) {
  const int i = blockIdx.x * 256 + threadIdx.x;  // global pair index
  const int npr = H * 32;
  const int t = i / npr;
  const int rem = i - t * npr;
  const int h = rem >> 5, fi = rem & 31;
  const float2 rein = *(const float2*)&src[(size_t)t * ldin + h * 64 + fi * 2];
  const float2 cs = *(const float2*)&fc[((size_t)t * 32 + fi) * 2];
  const float o0 = rein.x * cs.x - rein.y * cs.y;
  const float o1 = rein.x * cs.y + rein.y * cs.x;
  bf16x2 ob = {(bf16_t)o0, (bf16_t)o1};
  *(bf16x2*)&dst[(size_t)t * (H * 64) + h * 64 + fi * 2] = ob;
}

// ---------------- GEMM: C(f32, MxN) = A(bf16, MxK) * BT(bf16, NxK)^T ----------------
__global__ __launch_bounds__(256) void gemm_bt_kernel(
    const bf16_t* __restrict__ A, const bf16_t* __restrict__ BT,
    float* __restrict__ C, int M, int N, int K) {
  __shared__ bf16_t As[128 * 32];
  __shared__ bf16_t Bs[128 * 32];
  const int tid = threadIdx.x;
  const int lane = tid & 63;
  const int w = tid >> 6;
  const int lr = lane & 15, lg = lane >> 4;
  const int m0 = blockIdx.y * 128, n0 = blockIdx.x * 128;
  const int wm = (w >> 1) * 64, wn = (w & 1) * 64;

  const int c1 = tid, c2 = tid + 256;
  const bf16_t* gA1 = A + (size_t)(m0 + (c1 >> 2)) * K + (c1 & 3) * 8;
  const bf16_t* gA2 = A + (size_t)(m0 + (c2 >> 2)) * K + (c2 & 3) * 8;
  const bf16_t* gB1 = BT + (size_t)(n0 + (c1 >> 2)) * K + (c1 & 3) * 8;
  const bf16_t* gB2 = BT + (size_t)(n0 + (c2 >> 2)) * K + (c2 & 3) * 8;
  bf16_t* lA1 = As + c1 * 8;
  bf16_t* lA2 = As + c2 * 8;
  bf16_t* lB1 = Bs + c1 * 8;
  bf16_t* lB2 = Bs + c2 * 8;

  f32x4 acc[4][4] = {};

  for (int k0 = 0; k0 < K; k0 += 32) {
    gload_lds16(gA1 + k0, lA1);
    gload_lds16(gA2 + k0, lA2);
    gload_lds16(gB1 + k0, lB1);
    gload_lds16(gB2 + k0, lB2);
    __syncthreads();
    bf16x8 af[4], bfr[4];
#pragma unroll
    for (int mi = 0; mi < 4; ++mi)
      af[mi] = *(const bf16x8*)&As[(wm + mi * 16 + lr) * 32 + lg * 8];
#pragma unroll
    for (int nj = 0; nj < 4; ++nj)
      bfr[nj] = *(const bf16x8*)&Bs[(wn + nj * 16 + lr) * 32 + lg * 8];
#pragma unroll
    for (int mi = 0; mi < 4; ++mi)
#pragma unroll
      for (int nj = 0; nj < 4; ++nj)
        acc[mi][nj] = __builtin_amdgcn_mfma_f32_16x16x32_bf16(
            af[mi], bfr[nj], acc[mi][nj], 0, 0, 0);
    __syncthreads();
  }

#pragma unroll
  for (int mi = 0; mi < 4; ++mi)
#pragma unroll
    for (int nj = 0; nj < 4; ++nj) {
      const int row = m0 + wm + mi * 16 + lg * 4;
      const int col = n0 + wn + nj * 16 + lr;
#pragma unroll
      for (int r = 0; r < 4; ++r)
        C[(size_t)(row + r) * N + col] = acc[mi][nj][r];
    }
}

// ---------------- causal GQA flash attention (v2: swapped QK^T, in-lane softmax) ----
// grid = (T/64, NHEADS); block = 256 (4 waves, each owns 16 q-rows).
// Q: bf16 [T][2048], Kb: bf16 [T][512], VT: bf16 [512][T], Y: bf16 [T][2048]
__global__ __launch_bounds__(256) void attn_kernel(
    const bf16_t* __restrict__ Q, const bf16_t* __restrict__ Kb,
    const bf16_t* __restrict__ VT, bf16_t* __restrict__ Y) {
  __shared__ char plds_all[4][16 * 128];  // per-wave P tile [16 q][64 s] bf16, swizzled
  const int qt = (int)gridDim.x - 1 - (int)blockIdx.x;  // heavy blocks first
  const int h = blockIdx.y;
  const int kh = h >> 2;
  const int tid = threadIdx.x, lane = tid & 63, w = tid >> 6;
  const int lr = lane & 15, lg = lane >> 4;
  const int q0 = qt * 64 + w * 16;
  char* pb = plds_all[w];
  const int swz = (lr & 7) << 4;
  const float SCL = 0.18033688011112042f;  // 0.125 * log2(e)

  // Q fragments (B-operand of swapped QK^T): lane holds Q[q0+lr][d=ks*32+lg*8+e]
  bf16x8 qf[2];
#pragma unroll
  for (int ks = 0; ks < 2; ++ks)
    qf[ks] = *(const bf16x8*)&Q[(size_t)(q0 + lr) * NQD + h * HD + ks * 32 + lg * 8];

  float m_i = -1e30f, l_i = 0.f;  // state for q = q0 + lr (replicated across lg)
  f32x4 acc_o[4] = {};            // O[q=q0+lg*4+r][d=df*16+lr]

  for (int s0 = 0; s0 < q0 + 16; s0 += 64) {
    // K fragments (A-operand): lane holds K[s0+j*16+lr][d=ks*32+lg*8+e]
    bf16x8 kf[4][2];
#pragma unroll
    for (int j = 0; j < 4; ++j)
#pragma unroll
      for (int ks = 0; ks < 2; ++ks)
        kf[j][ks] = *(const bf16x8*)&Kb[(size_t)(s0 + j * 16 + lr) * NKVD + kh * HD + ks * 32 + lg * 8];

    // S^T = K · Q^T : lane holds S[q=q0+lr][s=s0+j*16+lg*4+r] in st[j][r]
    f32x4 st[4] = {};
    __builtin_amdgcn_s_setprio(1);
#pragma unroll
    for (int j = 0; j < 4; ++j)
#pragma unroll
      for (int ks = 0; ks < 2; ++ks)
        st[j] = __builtin_amdgcn_mfma_f32_16x16x32_bf16(kf[j][ks], qf[ks], st[j], 0, 0, 0);
    __builtin_amdgcn_s_setprio(0);

    // scale to log2 domain + causal mask (16 values, all in-lane)
    float sv[16];
    const bool domask = (s0 + 64 > q0);
    const int tq = q0 + lr;
#pragma unroll
    for (int j = 0; j < 4; ++j)
#pragma unroll
      for (int r = 0; r < 4; ++r) {
        float v = st[j][r] * SCL;
        if (domask && (s0 + j * 16 + lg * 4 + r > tq)) v = -1e30f;
        sv[j * 4 + r] = v;
      }

    // row max: in-lane tree + 2 cross-lane hops (lanes lr, lr+16, lr+32, lr+48)
    float pm = sv[0];
#pragma unroll
    for (int z = 1; z < 16; ++z) pm = fmaxf(pm, sv[z]);
    pm = fmaxf(pm, __shfl_xor(pm, 16));
    pm = fmaxf(pm, __shfl_xor(pm, 32));
    const float mnew = fmaxf(m_i, pm);
    const float es = exp2f(m_i - mnew);
    m_i = mnew;

    // exp + in-lane sum
    float rs = 0.f;
    bf16_t pe[16];
#pragma unroll
    for (int z = 0; z < 16; ++z) {
      const float p = exp2f(sv[z] - mnew);
      rs += p;
      pe[z] = (bf16_t)p;
    }
    rs += __shfl_xor(rs, 16);
    rs += __shfl_xor(rs, 32);
    l_i = l_i * es + rs;

    // store P to wave-private LDS, swizzled 8B chunks: P[q=lr][s=j*16+lg*4..+3]
#pragma unroll
    for (int j = 0; j < 4; ++j) {
      bf16x4 pk = {pe[j * 4 + 0], pe[j * 4 + 1], pe[j * 4 + 2], pe[j * 4 + 3]};
      *(bf16x4*)(pb + lr * 128 + ((j * 32 + lg * 8) ^ swz)) = pk;
    }

    // redistribute escale to O-row layout (row = lg*4+r lives in lane lr=row)
    float eso[4];
#pragma unroll
    for (int r = 0; r < 4; ++r) eso[r] = __shfl(es, lg * 4 + r);
#pragma unroll
    for (int df = 0; df < 4; ++df)
#pragma unroll
      for (int r = 0; r < 4; ++r) acc_o[df][r] *= eso[r];

    // P back as A-fragments: P[row=lr][k=ks*32+lg*8+e]
    bf16x8 pa[2];
#pragma unroll
    for (int ks = 0; ks < 2; ++ks)
      pa[ks] = *(const bf16x8*)(pb + lr * 128 + ((ks * 64 + lg * 16) ^ swz));

    // V fragments (B-operand) from transposed V
    bf16x8 vf[2][4];
#pragma unroll
    for (int ks = 0; ks < 2; ++ks)
#pragma unroll
      for (int df = 0; df < 4; ++df)
        vf[ks][df] = *(const bf16x8*)&VT[(size_t)(kh * HD + df * 16 + lr) * T_SEQ + s0 + ks * 32 + lg * 8];

    __builtin_amdgcn_s_setprio(1);
#pragma unroll
    for (int df = 0; df < 4; ++df)
#pragma unroll
      for (int ks = 0; ks < 2; ++ks)
        acc_o[df] = __builtin_amdgcn_mfma_f32_16x16x32_bf16(pa[ks], vf[ks][df], acc_o[df], 0, 0, 0);
    __builtin_amdgcn_s_setprio(0);
  }

  // normalize + write y (bf16); l for O-row lg*4+r lives in lane lr=row
  float lf[4];
#pragma unroll
  for (int r = 0; r < 4; ++r) lf[r] = __shfl(l_i, lg * 4 + r);
#pragma unroll
  for (int r = 0; r < 4; ++r) {
    const float inv = 1.f / lf[r];
    const int t = q0 + lg * 4 + r;
#pragma unroll
    for (int df = 0; df < 4; ++df)
      Y[(size_t)t * NQD + h * HD + df * 16 + lr] = (bf16_t)(acc_o[df][r] * inv);
  }
}

extern "C" void kernel_launch(void* const* d_in, const int* in_sizes, int n_in,
                              void* d_out, int out_size, void* d_ws, size_t ws_size,
                              hipStream_t stream) {
  const float* x = (const float*)d_in[0];
  const float* fc = (const float*)d_in[1];
  const float* wq = (const float*)d_in[2];
  const float* wk = (const float*)d_in[3];
  const float* wv = (const float*)d_in[4];
  const float* wo = (const float*)d_in[5];
  float* out = (float*)d_out;
  char* ws = (char*)d_ws;

  // workspace arena (36 MB), aliased by lifetime:
  bf16_t* xb   = (bf16_t*)(ws + 0);                 // [2048][2048]  8 MB
  bf16_t* wT   = (bf16_t*)(ws + (8u << 20));        // [3072][2048] 12 MB
  float*  qkvf = (float*)(ws + (20u << 20));        // [2048][3072] 24 MB fp32
  bf16_t* qb   = (bf16_t*)(ws + (8u << 20));        // [2048][2048]  8 MB (over wT)
  bf16_t* kb   = (bf16_t*)(ws + (16u << 20));       // [2048][512]   2 MB (over wT)
  bf16_t* vt   = (bf16_t*)(ws + (18u << 20));       // [512][2048]   2 MB (over wT)
  bf16_t* woT  = (bf16_t*)(ws + (20u << 20));       // [2048][2048]  8 MB (over qkvf)
  bf16_t* yb   = (bf16_t*)(ws + (28u << 20));       // [2048][2048]  8 MB (over qkvf)

  // 1. x -> bf16
  hipLaunchKernelGGL(cast_f32_bf16_kernel, dim3(2048), dim3(256), 0, stream,
                     x, xb, (T_SEQ * DMODEL) / 8);
  // 2. weight transposes into fused [3072][2048] B^T panel
  hipLaunchKernelGGL(transpose_cast_kernel, dim3(64, 64), dim3(256), 0, stream,
                     wq, wT, DMODEL, NQD, NQD, DMODEL);
  hipLaunchKernelGGL(transpose_cast_kernel, dim3(16, 64), dim3(256), 0, stream,
                     wk, wT + (size_t)NQD * DMODEL, DMODEL, NKVD, NKVD, DMODEL);
  hipLaunchKernelGGL(transpose_cast_kernel, dim3(16, 64), dim3(256), 0, stream,
                     wv, wT + (size_t)(NQD + NKVD) * DMODEL, DMODEL, NKVD, NKVD, DMODEL);
  // 3. fused QKV projection: qkvf = x @ [wq|wk|wv]
  hipLaunchKernelGGL(gemm_bt_kernel, dim3(QKVN / 128, T_SEQ / 128), dim3(256), 0, stream,
                     xb, wT, qkvf, T_SEQ, QKVN, DMODEL);
  // 4. RoPE + cast Q, K
  hipLaunchKernelGGL(rope_cast_kernel, dim3((T_SEQ * NHEADS * 32) / 256), dim3(256), 0, stream,
                     qkvf, fc, qb, NHEADS, QKVN);
  hipLaunchKernelGGL(rope_cast_kernel, dim3((T_SEQ * NKV * 32) / 256), dim3(256), 0, stream,
                     qkvf + NQD, fc, kb, NKV, QKVN);
  // 5. V -> VT (bf16, [512][2048])
  hipLaunchKernelGGL(transpose_cast_kernel, dim3(16, 64), dim3(256), 0, stream,
                     qkvf + NQD + NKVD, vt, T_SEQ, NKVD, QKVN, T_SEQ);
  // 6. wo -> woT
  hipLaunchKernelGGL(transpose_cast_kernel, dim3(64, 64), dim3(256), 0, stream,
                     wo, woT, NQD, DMODEL, DMODEL, NQD);
  // 7. attention
  hipLaunchKernelGGL(attn_kernel, dim3(T_SEQ / 64, NHEADS), dim3(256), 0, stream,
                     qb, kb, vt, yb);
  // 8. output projection -> d_out (fp32)
  hipLaunchKernelGGL(gemm_bt_kernel, dim3(DMODEL / 128, T_SEQ / 128), dim3(256), 0, stream,
                     yb, woT, out, T_SEQ, DMODEL, NQD);
}

// Round 3
// 236.610 us; speedup vs baseline: 1.6249x; 1.6249x over previous
//
#include <hip/hip_runtime.h>
#include <hip/hip_bf16.h>
#include <stdint.h>
#include <stddef.h>

#define T_SEQ 2048
#define DMODEL 2048
#define NHEADS 32
#define NKV 8
#define HD 64
#define NQD (NHEADS * HD)        // 2048
#define NKVD (NKV * HD)          // 512
#define QKVN (NQD + 2 * NKVD)    // 3072

typedef __bf16 bf16_t;
typedef __bf16 bf16x8 __attribute__((ext_vector_type(8)));
typedef __bf16 bf16x4 __attribute__((ext_vector_type(4)));
typedef __bf16 bf16x2 __attribute__((ext_vector_type(2)));
typedef float f32x4 __attribute__((ext_vector_type(4)));

typedef __attribute__((address_space(1))) void gvoid_t;
typedef __attribute__((address_space(3))) void lvoid_t;

__device__ __forceinline__ void gload_lds16(const void* g, void* l) {
  __builtin_amdgcn_global_load_lds((gvoid_t*)g, (lvoid_t*)l, 16, 0, 0);
}

// ---------------- elementwise cast f32 -> bf16 (8 elems/thread) ----------------
__global__ __launch_bounds__(256) void cast_f32_bf16_kernel(
    const float* __restrict__ in, bf16_t* __restrict__ out, int n8) {
  int i = blockIdx.x * 256 + threadIdx.x;
  if (i >= n8) return;
  const float4* p = (const float4*)in + (size_t)i * 2;
  float4 a = p[0], b = p[1];
  bf16x8 o = {(bf16_t)a.x, (bf16_t)a.y, (bf16_t)a.z, (bf16_t)a.w,
              (bf16_t)b.x, (bf16_t)b.y, (bf16_t)b.z, (bf16_t)b.w};
  *(bf16x8*)(out + (size_t)i * 8) = o;
}

// ---------------- tiled transpose + cast: out[c][r] = (bf16) in[r][c] ----------------
__global__ __launch_bounds__(256) void transpose_cast_kernel(
    const float* __restrict__ in, bf16_t* __restrict__ out,
    int R, int C, int ldin, int ldout) {
  __shared__ float tile[32][33];
  const int c0 = blockIdx.x * 32, r0 = blockIdx.y * 32;
  const int tx = threadIdx.x & 31, ty = threadIdx.x >> 5;
#pragma unroll
  for (int i = 0; i < 32; i += 8)
    tile[ty + i][tx] = in[(size_t)(r0 + ty + i) * ldin + c0 + tx];
  __syncthreads();
#pragma unroll
  for (int i = 0; i < 32; i += 8)
    out[(size_t)(c0 + ty + i) * ldout + r0 + tx] = (bf16_t)tile[tx][ty + i];
}

// ---------------- RoPE + cast ----------------
__global__ __launch_bounds__(256) void rope_cast_kernel(
    const float* __restrict__ src, const float* __restrict__ fc,
    bf16_t* __restrict__ dst, int H, int ldin) {
  const int i = blockIdx.x * 256 + threadIdx.x;  // global pair index
  const int npr = H * 32;
  const int t = i / npr;
  const int rem = i - t * npr;
  const int h = rem >> 5, fi = rem & 31;
  const float2 rein = *(const float2*)&src[(size_t)t * ldin + h * 64 + fi * 2];
  const float2 cs = *(const float2*)&fc[((size_t)t * 32 + fi) * 2];
  const float o0 = rein.x * cs.x - rein.y * cs.y;
  const float o1 = rein.x * cs.y + rein.y * cs.x;
  bf16x2 ob = {(bf16_t)o0, (bf16_t)o1};
  *(bf16x2*)&dst[(size_t)t * (H * 64) + h * 64 + fi * 2] = ob;
}

// ---------------- GEMM: C(f32, MxN) = A(bf16, MxK) * BT(bf16, NxK)^T ----------------
__global__ __launch_bounds__(256) void gemm_bt_kernel(
    const bf16_t* __restrict__ A, const bf16_t* __restrict__ BT,
    float* __restrict__ C, int M, int N, int K) {
  __shared__ bf16_t As[128 * 32];
  __shared__ bf16_t Bs[128 * 32];
  const int tid = threadIdx.x;
  const int lane = tid & 63;
  const int w = tid >> 6;
  const int lr = lane & 15, lg = lane >> 4;
  const int m0 = blockIdx.y * 128, n0 = blockIdx.x * 128;
  const int wm = (w >> 1) * 64, wn = (w & 1) * 64;

  const int c1 = tid, c2 = tid + 256;
  const bf16_t* gA1 = A + (size_t)(m0 + (c1 >> 2)) * K + (c1 & 3) * 8;
  const bf16_t* gA2 = A + (size_t)(m0 + (c2 >> 2)) * K + (c2 & 3) * 8;
  const bf16_t* gB1 = BT + (size_t)(n0 + (c1 >> 2)) * K + (c1 & 3) * 8;
  const bf16_t* gB2 = BT + (size_t)(n0 + (c2 >> 2)) * K + (c2 & 3) * 8;
  bf16_t* lA1 = As + c1 * 8;
  bf16_t* lA2 = As + c2 * 8;
  bf16_t* lB1 = Bs + c1 * 8;
  bf16_t* lB2 = Bs + c2 * 8;

  f32x4 acc[4][4] = {};

  for (int k0 = 0; k0 < K; k0 += 32) {
    gload_lds16(gA1 + k0, lA1);
    gload_lds16(gA2 + k0, lA2);
    gload_lds16(gB1 + k0, lB1);
    gload_lds16(gB2 + k0, lB2);
    __syncthreads();
    bf16x8 af[4], bfr[4];
#pragma unroll
    for (int mi = 0; mi < 4; ++mi)
      af[mi] = *(const bf16x8*)&As[(wm + mi * 16 + lr) * 32 + lg * 8];
#pragma unroll
    for (int nj = 0; nj < 4; ++nj)
      bfr[nj] = *(const bf16x8*)&Bs[(wn + nj * 16 + lr) * 32 + lg * 8];
#pragma unroll
    for (int mi = 0; mi < 4; ++mi)
#pragma unroll
      for (int nj = 0; nj < 4; ++nj)
        acc[mi][nj] = __builtin_amdgcn_mfma_f32_16x16x32_bf16(
            af[mi], bfr[nj], acc[mi][nj], 0, 0, 0);
    __syncthreads();
  }

#pragma unroll
  for (int mi = 0; mi < 4; ++mi)
#pragma unroll
    for (int nj = 0; nj < 4; ++nj) {
      const int row = m0 + wm + mi * 16 + lg * 4;
      const int col = n0 + wn + nj * 16 + lr;
#pragma unroll
      for (int r = 0; r < 4; ++r)
        C[(size_t)(row + r) * N + col] = acc[mi][nj][r];
    }
}

// ---------------- causal GQA flash attention v3 ----------------
// grid = (T/32, NKV); block = 256 = 4 waves = the 4 q-heads of one kv-head.
// Each wave: 32 q-rows of head h = kh*4+w at rows [qt*32, qt*32+32).
// K tile [64 s][64 d] and V^T tile [64 d][64 s] staged in LDS (shared by all
// 4 waves), double-buffered, XOR-swizzled (byte ^= (row&7)<<4) via
// pre-swizzled global source (global_load_lds writes lane-linear).
__global__ __launch_bounds__(256) void attn_kernel(
    const bf16_t* __restrict__ Q, const bf16_t* __restrict__ Kb,
    const bf16_t* __restrict__ VT, bf16_t* __restrict__ Y) {
  __shared__ bf16_t Ks[2][64 * 64];
  __shared__ bf16_t Vs[2][64 * 64];
  __shared__ char Pb[4][32 * 128];
  const int qt = (int)gridDim.x - 1 - (int)blockIdx.x;  // heavy blocks first
  const int kh = blockIdx.y;
  const int tid = threadIdx.x, lane = tid & 63, w = tid >> 6;
  const int h = kh * 4 + w;
  const int lr = lane & 15, lg = lane >> 4;
  const int q0 = qt * 32;
  char* pb = (char*)Pb[w];
  const int swz = (lr & 7) << 4;
  const float SCL = 0.18033688011112042f;  // (1/8) * log2(e)

  // staging: wave w stages rows [w*8, w*8+8) and [(w+4)*8, +8) of both tiles.
  // source chunk pre-swizzled: c = (lane&7) ^ (row&7), row&7 == lane>>3.
  const int rA = w * 8 + (lane >> 3);
  const int rB = (w + 4) * 8 + (lane >> 3);
  const int ce = (((lane & 7) ^ (lane >> 3)) * 8);  // element col offset
  const bf16_t* kgA = Kb + (size_t)rA * NKVD + kh * HD + ce;
  const bf16_t* kgB = Kb + (size_t)rB * NKVD + kh * HD + ce;
  const bf16_t* vgA = VT + (size_t)(kh * HD + rA) * T_SEQ + ce;
  const bf16_t* vgB = VT + (size_t)(kh * HD + rB) * T_SEQ + ce;
  const int ldA = w * 512 + lane * 8;        // lane-linear LDS dest (elems)
  const int ldB = (w + 4) * 512 + lane * 8;

  // Q fragments (B operand of swapped QK^T): Q[q0+iq*16+lr][ks*32+lg*8+e]
  bf16x8 qf[2][2];
#pragma unroll
  for (int iq = 0; iq < 2; ++iq)
#pragma unroll
    for (int ks = 0; ks < 2; ++ks)
      qf[iq][ks] = *(const bf16x8*)&Q[(size_t)(q0 + iq * 16 + lr) * NQD + h * HD + ks * 32 + lg * 8];

  float m_i[2] = {-1e30f, -1e30f}, l_i[2] = {0.f, 0.f};
  f32x4 acc_o[2][4] = {};  // O[q=iq*16+lg*4+r][d=df*16+lr]

  const int nt = (qt + 2) >> 1;  // KV tiles of 64
  // prologue: stage tile 0 into buffer 0
  gload_lds16(kgA, &Ks[0][ldA]);
  gload_lds16(kgB, &Ks[0][ldB]);
  gload_lds16(vgA, &Vs[0][ldA]);
  gload_lds16(vgB, &Vs[0][ldB]);
  __syncthreads();

  int cur = 0;
  for (int t = 0; t < nt; ++t) {
    const int s0 = t * 64;
    if (t + 1 < nt) {  // stage next tile into other buffer (overlaps compute)
      const size_t ko = (size_t)(s0 + 64) * NKVD;
      gload_lds16(kgA + ko, &Ks[cur ^ 1][ldA]);
      gload_lds16(kgB + ko, &Ks[cur ^ 1][ldB]);
      gload_lds16(vgA + s0 + 64, &Vs[cur ^ 1][ldA]);
      gload_lds16(vgB + s0 + 64, &Vs[cur ^ 1][ldB]);
    }
    const char* kbase = (const char*)&Ks[cur][0];
    const char* vbase = (const char*)&Vs[cur][0];

    // K fragments (A operand): K[s=j*16+lr][d=ks*32+lg*8+e], swizzled read
    bf16x8 kf[4][2];
#pragma unroll
    for (int j = 0; j < 4; ++j)
#pragma unroll
      for (int ks = 0; ks < 2; ++ks)
        kf[j][ks] = *(const bf16x8*)(kbase + (j * 16 + lr) * 128 + ((ks * 64 + lg * 16) ^ swz));

    // S^T = K·Q^T : lane holds S[q=q0+iq*16+lr][s=s0+j*16+lg*4+r]
    f32x4 st[2][4] = {};
    __builtin_amdgcn_s_setprio(1);
#pragma unroll
    for (int iq = 0; iq < 2; ++iq)
#pragma unroll
      for (int j = 0; j < 4; ++j)
#pragma unroll
        for (int ks = 0; ks < 2; ++ks)
          st[iq][j] = __builtin_amdgcn_mfma_f32_16x16x32_bf16(kf[j][ks], qf[iq][ks], st[iq][j], 0, 0, 0);
    __builtin_amdgcn_s_setprio(0);

    const bool domask = (s0 + 64 > q0);  // block-uniform
#pragma unroll
    for (int iq = 0; iq < 2; ++iq) {
      float sv[16];
      const int tq = q0 + iq * 16 + lr;
#pragma unroll
      for (int j = 0; j < 4; ++j)
#pragma unroll
        for (int r = 0; r < 4; ++r) {
          float v = st[iq][j][r] * SCL;
          if (domask && (s0 + j * 16 + lg * 4 + r > tq)) v = -1e30f;
          sv[j * 4 + r] = v;
        }
      // row max: in-lane tree + 2 hops (row q replicated in lanes lr+16*lg)
      float pm = fmaxf(fmaxf(fmaxf(sv[0], sv[1]), fmaxf(sv[2], sv[3])),
                       fmaxf(fmaxf(sv[4], sv[5]), fmaxf(sv[6], sv[7])));
      float pm2 = fmaxf(fmaxf(fmaxf(sv[8], sv[9]), fmaxf(sv[10], sv[11])),
                        fmaxf(fmaxf(sv[12], sv[13]), fmaxf(sv[14], sv[15])));
      pm = fmaxf(pm, pm2);
      pm = fmaxf(pm, __shfl_xor(pm, 16));
      pm = fmaxf(pm, __shfl_xor(pm, 32));
      const float mnew = fmaxf(m_i[iq], pm);
      const float es = exp2f(m_i[iq] - mnew);
      m_i[iq] = mnew;

      float rs = 0.f;
      bf16_t pe[16];
#pragma unroll
      for (int z = 0; z < 16; ++z) {
        const float p = exp2f(sv[z] - mnew);
        rs += p;
        pe[z] = (bf16_t)p;
      }
      rs += __shfl_xor(rs, 16);
      rs += __shfl_xor(rs, 32);
      l_i[iq] = l_i[iq] * es + rs;

      // store P rows to wave-private swizzled LDS: P[q=iq*16+lr][s=j*16+lg*4..+3]
#pragma unroll
      for (int j = 0; j < 4; ++j) {
        bf16x4 pk = {pe[j * 4 + 0], pe[j * 4 + 1], pe[j * 4 + 2], pe[j * 4 + 3]};
        *(bf16x4*)(pb + (iq * 16 + lr) * 128 + ((j * 32 + lg * 8) ^ swz)) = pk;
      }

      // rescale O (row iq*16+lg*4+r's escale lives in lane lr=lg*4+r)
      float eso[4];
#pragma unroll
      for (int r = 0; r < 4; ++r) eso[r] = __shfl(es, lg * 4 + r);
#pragma unroll
      for (int df = 0; df < 4; ++df)
#pragma unroll
        for (int r = 0; r < 4; ++r) acc_o[iq][df][r] *= eso[r];
    }

    // P back as A fragments: P[q=iq*16+lr][k=ks*32+lg*8+e]
    bf16x8 pa[2][2];
#pragma unroll
    for (int iq = 0; iq < 2; ++iq)
#pragma unroll
      for (int ks = 0; ks < 2; ++ks)
        pa[iq][ks] = *(const bf16x8*)(pb + (iq * 16 + lr) * 128 + ((ks * 64 + lg * 16) ^ swz));

    // V fragments (B operand): V[s=ks*32+lg*8+e][d=df*16+lr], swizzled read
    bf16x8 vf[2][4];
#pragma unroll
    for (int ks = 0; ks < 2; ++ks)
#pragma unroll
      for (int df = 0; df < 4; ++df)
        vf[ks][df] = *(const bf16x8*)(vbase + (df * 16 + lr) * 128 + ((ks * 64 + lg * 16) ^ swz));

    __builtin_amdgcn_s_setprio(1);
#pragma unroll
    for (int iq = 0; iq < 2; ++iq)
#pragma unroll
      for (int df = 0; df < 4; ++df)
#pragma unroll
        for (int ks = 0; ks < 2; ++ks)
          acc_o[iq][df] = __builtin_amdgcn_mfma_f32_16x16x32_bf16(pa[iq][ks], vf[ks][df], acc_o[iq][df], 0, 0, 0);
    __builtin_amdgcn_s_setprio(0);

    __syncthreads();
    cur ^= 1;
  }

  // normalize + write y
#pragma unroll
  for (int iq = 0; iq < 2; ++iq) {
    float lf[4];
#pragma unroll
    for (int r = 0; r < 4; ++r) lf[r] = __shfl(l_i[iq], lg * 4 + r);
#pragma unroll
    for (int r = 0; r < 4; ++r) {
      const float inv = 1.f / lf[r];
      const int t = q0 + iq * 16 + lg * 4 + r;
#pragma unroll
      for (int df = 0; df < 4; ++df)
        Y[(size_t)t * NQD + h * HD + df * 16 + lr] = (bf16_t)(acc_o[iq][df][r] * inv);
    }
  }
}

extern "C" void kernel_launch(void* const* d_in, const int* in_sizes, int n_in,
                              void* d_out, int out_size, void* d_ws, size_t ws_size,
                              hipStream_t stream) {
  const float* x = (const float*)d_in[0];
  const float* fc = (const float*)d_in[1];
  const float* wq = (const float*)d_in[2];
  const float* wk = (const float*)d_in[3];
  const float* wv = (const float*)d_in[4];
  const float* wo = (const float*)d_in[5];
  float* out = (float*)d_out;
  char* ws = (char*)d_ws;

  // workspace arena (36 MB), aliased by lifetime:
  bf16_t* xb   = (bf16_t*)(ws + 0);                 // [2048][2048]  8 MB
  bf16_t* wT   = (bf16_t*)(ws + (8u << 20));        // [3072][2048] 12 MB
  float*  qkvf = (float*)(ws + (20u << 20));        // [2048][3072] 24 MB fp32
  bf16_t* qb   = (bf16_t*)(ws + (8u << 20));        // [2048][2048]  8 MB (over wT)
  bf16_t* kb   = (bf16_t*)(ws + (16u << 20));       // [2048][512]   2 MB (over wT)
  bf16_t* vt   = (bf16_t*)(ws + (18u << 20));       // [512][2048]   2 MB (over wT)
  bf16_t* woT  = (bf16_t*)(ws + (20u << 20));       // [2048][2048]  8 MB (over qkvf)
  bf16_t* yb   = (bf16_t*)(ws + (28u << 20));       // [2048][2048]  8 MB (over qkvf)

  // 1. x -> bf16
  hipLaunchKernelGGL(cast_f32_bf16_kernel, dim3(2048), dim3(256), 0, stream,
                     x, xb, (T_SEQ * DMODEL) / 8);
  // 2. weight transposes into fused [3072][2048] B^T panel
  hipLaunchKernelGGL(transpose_cast_kernel, dim3(64, 64), dim3(256), 0, stream,
                     wq, wT, DMODEL, NQD, NQD, DMODEL);
  hipLaunchKernelGGL(transpose_cast_kernel, dim3(16, 64), dim3(256), 0, stream,
                     wk, wT + (size_t)NQD * DMODEL, DMODEL, NKVD, NKVD, DMODEL);
  hipLaunchKernelGGL(transpose_cast_kernel, dim3(16, 64), dim3(256), 0, stream,
                     wv, wT + (size_t)(NQD + NKVD) * DMODEL, DMODEL, NKVD, NKVD, DMODEL);
  // 3. fused QKV projection: qkvf = x @ [wq|wk|wv]
  hipLaunchKernelGGL(gemm_bt_kernel, dim3(QKVN / 128, T_SEQ / 128), dim3(256), 0, stream,
                     xb, wT, qkvf, T_SEQ, QKVN, DMODEL);
  // 4. RoPE + cast Q, K
  hipLaunchKernelGGL(rope_cast_kernel, dim3((T_SEQ * NHEADS * 32) / 256), dim3(256), 0, stream,
                     qkvf, fc, qb, NHEADS, QKVN);
  hipLaunchKernelGGL(rope_cast_kernel, dim3((T_SEQ * NKV * 32) / 256), dim3(256), 0, stream,
                     qkvf + NQD, fc, kb, NKV, QKVN);
  // 5. V -> VT (bf16, [512][2048])
  hipLaunchKernelGGL(transpose_cast_kernel, dim3(16, 64), dim3(256), 0, stream,
                     qkvf + NQD + NKVD, vt, T_SEQ, NKVD, QKVN, T_SEQ);
  // 6. wo -> woT
  hipLaunchKernelGGL(transpose_cast_kernel, dim3(64, 64), dim3(256), 0, stream,
                     wo, woT, NQD, DMODEL, DMODEL, NQD);
  // 7. attention
  hipLaunchKernelGGL(attn_kernel, dim3(T_SEQ / 32, NKV), dim3(256), 0, stream,
                     qb, kb, vt, yb);
  // 8. output projection -> d_out (fp32)
  hipLaunchKernelGGL(gemm_bt_kernel, dim3(DMODEL / 128, T_SEQ / 128), dim3(256), 0, stream,
                     yb, woT, out, T_SEQ, DMODEL, NQD);
}

// Round 4
// 190.200 us; speedup vs baseline: 2.0214x; 1.2440x over previous
//
#include <hip/hip_runtime.h>
#include <hip/hip_bf16.h>
#include <stdint.h>
#include <stddef.h>

#define T_SEQ 2048
#define DMODEL 2048
#define NHEADS 32
#define NKV 8
#define HD 64
#define NQD (NHEADS * HD)        // 2048
#define NKVD (NKV * HD)          // 512
#define QKVN (NQD + 2 * NKVD)    // 3072

typedef __bf16 bf16_t;
typedef __bf16 bf16x8 __attribute__((ext_vector_type(8)));
typedef __bf16 bf16x4 __attribute__((ext_vector_type(4)));
typedef __bf16 bf16x2 __attribute__((ext_vector_type(2)));
typedef float f32x4 __attribute__((ext_vector_type(4)));

typedef __attribute__((address_space(1))) void gvoid_t;
typedef __attribute__((address_space(3))) void lvoid_t;

__device__ __forceinline__ void gload_lds16(const void* g, void* l) {
  __builtin_amdgcn_global_load_lds((gvoid_t*)g, (lvoid_t*)l, 16, 0, 0);
}

// ---------------- elementwise cast f32 -> bf16 (8 elems/thread) ----------------
__global__ __launch_bounds__(256) void cast_f32_bf16_kernel(
    const float* __restrict__ in, bf16_t* __restrict__ out, int n8) {
  int i = blockIdx.x * 256 + threadIdx.x;
  if (i >= n8) return;
  const float4* p = (const float4*)in + (size_t)i * 2;
  float4 a = p[0], b = p[1];
  bf16x8 o = {(bf16_t)a.x, (bf16_t)a.y, (bf16_t)a.z, (bf16_t)a.w,
              (bf16_t)b.x, (bf16_t)b.y, (bf16_t)b.z, (bf16_t)b.w};
  *(bf16x8*)(out + (size_t)i * 8) = o;
}

// ---------------- tiled transpose + cast: out[c][r] = (bf16) in[r][c] ----------------
__global__ __launch_bounds__(256) void transpose_cast_kernel(
    const float* __restrict__ in, bf16_t* __restrict__ out,
    int R, int C, int ldin, int ldout) {
  __shared__ float tile[32][33];
  const int c0 = blockIdx.x * 32, r0 = blockIdx.y * 32;
  const int tx = threadIdx.x & 31, ty = threadIdx.x >> 5;
#pragma unroll
  for (int i = 0; i < 32; i += 8)
    tile[ty + i][tx] = in[(size_t)(r0 + ty + i) * ldin + c0 + tx];
  __syncthreads();
#pragma unroll
  for (int i = 0; i < 32; i += 8)
    out[(size_t)(c0 + ty + i) * ldout + r0 + tx] = (bf16_t)tile[tx][ty + i];
}

// ---------------- RoPE + cast (oscale folds attention scale into Q) ----------------
__global__ __launch_bounds__(256) void rope_cast_kernel(
    const float* __restrict__ src, const float* __restrict__ fc,
    bf16_t* __restrict__ dst, int H, int ldin, float oscale) {
  const int i = blockIdx.x * 256 + threadIdx.x;  // global pair index
  const int npr = H * 32;
  const int t = i / npr;
  const int rem = i - t * npr;
  const int h = rem >> 5, fi = rem & 31;
  const float2 rein = *(const float2*)&src[(size_t)t * ldin + h * 64 + fi * 2];
  const float2 cs = *(const float2*)&fc[((size_t)t * 32 + fi) * 2];
  const float o0 = (rein.x * cs.x - rein.y * cs.y) * oscale;
  const float o1 = (rein.x * cs.y + rein.y * cs.x) * oscale;
  bf16x2 ob = {(bf16_t)o0, (bf16_t)o1};
  *(bf16x2*)&dst[(size_t)t * (H * 64) + h * 64 + fi * 2] = ob;
}

// ---------------- GEMM: C(f32, MxN) = A(bf16, MxK) * BT(bf16, NxK)^T ----------------
// 128(M)x64(N) tile, BK=64, 256 threads (4 waves 2x2 -> 64x32 each),
// XOR-swizzled LDS staged via global_load_lds (pre-swizzled source).
__global__ __launch_bounds__(256) void gemm_bt64_kernel(
    const bf16_t* __restrict__ A, const bf16_t* __restrict__ BT,
    float* __restrict__ C, int M, int N, int K) {
  __shared__ bf16_t As[128 * 64];  // 16KB
  __shared__ bf16_t Bs[64 * 64];   // 8KB
  const int tid = threadIdx.x;
  const int lane = tid & 63;
  const int w = tid >> 6;
  const int lr = lane & 15, lg = lane >> 4;
  const int m0 = blockIdx.y * 128, n0 = blockIdx.x * 64;
  const int wm = (w >> 1) * 64, wn = (w & 1) * 32;

  // staging pointers: A 1024 chunks of 16B (4/thread), B 512 (2/thread)
  const bf16_t* gA[4];
  bf16_t* lA[4];
#pragma unroll
  for (int j = 0; j < 4; ++j) {
    const int c = tid + j * 256;
    const int row = c >> 3, cc = c & 7;
    gA[j] = A + (size_t)(m0 + row) * K + ((cc ^ (row & 7)) * 8);
    lA[j] = As + c * 8;
  }
  const bf16_t* gB[2];
  bf16_t* lB[2];
#pragma unroll
  for (int j = 0; j < 2; ++j) {
    const int c = tid + j * 256;
    const int row = c >> 3, cc = c & 7;
    gB[j] = BT + (size_t)(n0 + row) * K + ((cc ^ (row & 7)) * 8);
    lB[j] = Bs + c * 8;
  }

  f32x4 acc[4][2] = {};

  for (int k0 = 0; k0 < K; k0 += 64) {
#pragma unroll
    for (int j = 0; j < 4; ++j) gload_lds16(gA[j] + k0, lA[j]);
#pragma unroll
    for (int j = 0; j < 2; ++j) gload_lds16(gB[j] + k0, lB[j]);
    __syncthreads();
#pragma unroll
    for (int ks = 0; ks < 2; ++ks) {
      bf16x8 af[4], bfr[2];
#pragma unroll
      for (int mi = 0; mi < 4; ++mi) {
        const int row = wm + mi * 16 + lr;
        af[mi] = *(const bf16x8*)((const char*)As + row * 128 +
                                  ((ks * 64 + lg * 16) ^ ((row & 7) << 4)));
      }
#pragma unroll
      for (int nj = 0; nj < 2; ++nj) {
        const int row = wn + nj * 16 + lr;
        bfr[nj] = *(const bf16x8*)((const char*)Bs + row * 128 +
                                   ((ks * 64 + lg * 16) ^ ((row & 7) << 4)));
      }
      __builtin_amdgcn_s_setprio(1);
#pragma unroll
      for (int mi = 0; mi < 4; ++mi)
#pragma unroll
        for (int nj = 0; nj < 2; ++nj)
          acc[mi][nj] = __builtin_amdgcn_mfma_f32_16x16x32_bf16(
              af[mi], bfr[nj], acc[mi][nj], 0, 0, 0);
      __builtin_amdgcn_s_setprio(0);
    }
    __syncthreads();
  }

#pragma unroll
  for (int mi = 0; mi < 4; ++mi)
#pragma unroll
    for (int nj = 0; nj < 2; ++nj) {
      const int row = m0 + wm + mi * 16 + lg * 4;
      const int col = n0 + wn + nj * 16 + lr;
#pragma unroll
      for (int r = 0; r < 4; ++r)
        C[(size_t)(row + r) * N + col] = acc[mi][nj][r];
    }
}

// ---------------- causal GQA flash attention v4 ----------------
// grid = (T/32, NKV); block = 256 = 4 waves = the 4 q-heads of one kv-head.
// v4: Q pre-scaled (exp2 domain), defer-max (THR=8), lane-partial l,
// V fragment reads hoisted above softmax.
__global__ __launch_bounds__(256) void attn_kernel(
    const bf16_t* __restrict__ Q, const bf16_t* __restrict__ Kb,
    const bf16_t* __restrict__ VT, bf16_t* __restrict__ Y) {
  __shared__ bf16_t Ks[2][64 * 64];
  __shared__ bf16_t Vs[2][64 * 64];
  __shared__ char Pb[4][32 * 128];
  const int qt = (int)gridDim.x - 1 - (int)blockIdx.x;  // heavy blocks first
  const int kh = blockIdx.y;
  const int tid = threadIdx.x, lane = tid & 63, w = tid >> 6;
  const int h = kh * 4 + w;
  const int lr = lane & 15, lg = lane >> 4;
  const int q0 = qt * 32;
  char* pb = (char*)Pb[w];
  const int swz = (lr & 7) << 4;

  // staging: wave w stages rows [w*8,+8) and [(w+4)*8,+8) of K and V^T tiles.
  const int rA = w * 8 + (lane >> 3);
  const int rB = (w + 4) * 8 + (lane >> 3);
  const int ce = (((lane & 7) ^ (lane >> 3)) * 8);  // pre-swizzled col chunk
  const bf16_t* kgA = Kb + (size_t)rA * NKVD + kh * HD + ce;
  const bf16_t* kgB = Kb + (size_t)rB * NKVD + kh * HD + ce;
  const bf16_t* vgA = VT + (size_t)(kh * HD + rA) * T_SEQ + ce;
  const bf16_t* vgB = VT + (size_t)(kh * HD + rB) * T_SEQ + ce;
  const int ldA = w * 512 + lane * 8;
  const int ldB = (w + 4) * 512 + lane * 8;

  // Q fragments (B operand of swapped QK^T): Q[q0+iq*16+lr][ks*32+lg*8+e]
  bf16x8 qf[2][2];
#pragma unroll
  for (int iq = 0; iq < 2; ++iq)
#pragma unroll
    for (int ks = 0; ks < 2; ++ks)
      qf[iq][ks] = *(const bf16x8*)&Q[(size_t)(q0 + iq * 16 + lr) * NQD + h * HD + ks * 32 + lg * 8];

  float m_i[2] = {-1e30f, -1e30f}, l_i[2] = {0.f, 0.f};  // l is lane-partial
  f32x4 acc_o[2][4] = {};  // O[q=iq*16+lg*4+r][d=df*16+lr]

  const int nt = (qt + 2) >> 1;  // KV tiles of 64
  gload_lds16(kgA, &Ks[0][ldA]);
  gload_lds16(kgB, &Ks[0][ldB]);
  gload_lds16(vgA, &Vs[0][ldA]);
  gload_lds16(vgB, &Vs[0][ldB]);
  __syncthreads();

  int cur = 0;
  for (int t = 0; t < nt; ++t) {
    const int s0 = t * 64;
    if (t + 1 < nt) {
      const size_t ko = (size_t)(s0 + 64) * NKVD;
      gload_lds16(kgA + ko, &Ks[cur ^ 1][ldA]);
      gload_lds16(kgB + ko, &Ks[cur ^ 1][ldB]);
      gload_lds16(vgA + s0 + 64, &Vs[cur ^ 1][ldA]);
      gload_lds16(vgB + s0 + 64, &Vs[cur ^ 1][ldB]);
    }
    const char* kbase = (const char*)&Ks[cur][0];
    const char* vbase = (const char*)&Vs[cur][0];

    // K fragments (A operand)
    bf16x8 kf[4][2];
#pragma unroll
    for (int j = 0; j < 4; ++j)
#pragma unroll
      for (int ks = 0; ks < 2; ++ks)
        kf[j][ks] = *(const bf16x8*)(kbase + (j * 16 + lr) * 128 + ((ks * 64 + lg * 16) ^ swz));

    // S^T = K·Q^T (already in exp2 domain: Q pre-scaled by 0.125*log2e)
    f32x4 st[2][4] = {};
    __builtin_amdgcn_s_setprio(1);
#pragma unroll
    for (int iq = 0; iq < 2; ++iq)
#pragma unroll
      for (int j = 0; j < 4; ++j)
#pragma unroll
        for (int ks = 0; ks < 2; ++ks)
          st[iq][j] = __builtin_amdgcn_mfma_f32_16x16x32_bf16(kf[j][ks], qf[iq][ks], st[iq][j], 0, 0, 0);
    __builtin_amdgcn_s_setprio(0);

    // V fragments hoisted (independent of softmax)
    bf16x8 vf[2][4];
#pragma unroll
    for (int ks = 0; ks < 2; ++ks)
#pragma unroll
      for (int df = 0; df < 4; ++df)
        vf[ks][df] = *(const bf16x8*)(vbase + (df * 16 + lr) * 128 + ((ks * 64 + lg * 16) ^ swz));

    const bool domask = (s0 + 64 > q0);  // block-uniform
#pragma unroll
    for (int iq = 0; iq < 2; ++iq) {
      float sv[16];
      const int tq = q0 + iq * 16 + lr;
#pragma unroll
      for (int j = 0; j < 4; ++j)
#pragma unroll
        for (int r = 0; r < 4; ++r) {
          float v = st[iq][j][r];
          if (domask && (s0 + j * 16 + lg * 4 + r > tq)) v = -1e30f;
          sv[j * 4 + r] = v;
        }
      // row max: in-lane tree + 2 hops
      float pm = fmaxf(fmaxf(fmaxf(sv[0], sv[1]), fmaxf(sv[2], sv[3])),
                       fmaxf(fmaxf(sv[4], sv[5]), fmaxf(sv[6], sv[7])));
      float pm2 = fmaxf(fmaxf(fmaxf(sv[8], sv[9]), fmaxf(sv[10], sv[11])),
                        fmaxf(fmaxf(sv[12], sv[13]), fmaxf(sv[14], sv[15])));
      pm = fmaxf(pm, pm2);
      pm = fmaxf(pm, __shfl_xor(pm, 16));
      pm = fmaxf(pm, __shfl_xor(pm, 32));

      // defer-max: only rescale when some row grew by > 8 (rare after tile 0)
      if (!__all(pm <= m_i[iq] + 8.0f)) {
        const float mnew = fmaxf(m_i[iq], pm);
        const float es = exp2f(m_i[iq] - mnew);
        m_i[iq] = mnew;
        l_i[iq] *= es;
        float eso[4];
#pragma unroll
        for (int r = 0; r < 4; ++r) eso[r] = __shfl(es, lg * 4 + r);
#pragma unroll
        for (int df = 0; df < 4; ++df)
#pragma unroll
          for (int r = 0; r < 4; ++r) acc_o[iq][df][r] *= eso[r];
      }

      // exp + lane-partial sum; P bounded by 2^8
      float rs0 = 0.f, rs1 = 0.f;
      bf16_t pe[16];
#pragma unroll
      for (int z = 0; z < 8; ++z) {
        const float p = exp2f(sv[z] - m_i[iq]);
        rs0 += p;
        pe[z] = (bf16_t)p;
      }
#pragma unroll
      for (int z = 8; z < 16; ++z) {
        const float p = exp2f(sv[z] - m_i[iq]);
        rs1 += p;
        pe[z] = (bf16_t)p;
      }
      l_i[iq] += rs0 + rs1;

      // store P rows to wave-private swizzled LDS
#pragma unroll
      for (int j = 0; j < 4; ++j) {
        bf16x4 pk = {pe[j * 4 + 0], pe[j * 4 + 1], pe[j * 4 + 2], pe[j * 4 + 3]};
        *(bf16x4*)(pb + (iq * 16 + lr) * 128 + ((j * 32 + lg * 8) ^ swz)) = pk;
      }
    }

    // P back as A fragments
    bf16x8 pa[2][2];
#pragma unroll
    for (int iq = 0; iq < 2; ++iq)
#pragma unroll
      for (int ks = 0; ks < 2; ++ks)
        pa[iq][ks] = *(const bf16x8*)(pb + (iq * 16 + lr) * 128 + ((ks * 64 + lg * 16) ^ swz));

    __builtin_amdgcn_s_setprio(1);
#pragma unroll
    for (int iq = 0; iq < 2; ++iq)
#pragma unroll
      for (int df = 0; df < 4; ++df)
#pragma unroll
        for (int ks = 0; ks < 2; ++ks)
          acc_o[iq][df] = __builtin_amdgcn_mfma_f32_16x16x32_bf16(pa[iq][ks], vf[ks][df], acc_o[iq][df], 0, 0, 0);
    __builtin_amdgcn_s_setprio(0);

    __syncthreads();
    cur ^= 1;
  }

  // final l reduction + normalize + write y
#pragma unroll
  for (int iq = 0; iq < 2; ++iq) {
    float lt = l_i[iq];
    lt += __shfl_xor(lt, 16);
    lt += __shfl_xor(lt, 32);
    float lf[4];
#pragma unroll
    for (int r = 0; r < 4; ++r) lf[r] = __shfl(lt, lg * 4 + r);
#pragma unroll
    for (int r = 0; r < 4; ++r) {
      const float inv = 1.f / lf[r];
      const int t = q0 + iq * 16 + lg * 4 + r;
#pragma unroll
      for (int df = 0; df < 4; ++df)
        Y[(size_t)t * NQD + h * HD + df * 16 + lr] = (bf16_t)(acc_o[iq][df][r] * inv);
    }
  }
}

extern "C" void kernel_launch(void* const* d_in, const int* in_sizes, int n_in,
                              void* d_out, int out_size, void* d_ws, size_t ws_size,
                              hipStream_t stream) {
  const float* x = (const float*)d_in[0];
  const float* fc = (const float*)d_in[1];
  const float* wq = (const float*)d_in[2];
  const float* wk = (const float*)d_in[3];
  const float* wv = (const float*)d_in[4];
  const float* wo = (const float*)d_in[5];
  float* out = (float*)d_out;
  char* ws = (char*)d_ws;

  // workspace arena (36 MB), aliased by lifetime:
  bf16_t* xb   = (bf16_t*)(ws + 0);                 // [2048][2048]  8 MB
  bf16_t* wT   = (bf16_t*)(ws + (8u << 20));        // [3072][2048] 12 MB
  float*  qkvf = (float*)(ws + (20u << 20));        // [2048][3072] 24 MB fp32
  bf16_t* qb   = (bf16_t*)(ws + (8u << 20));        // [2048][2048]  8 MB (over wT)
  bf16_t* kb   = (bf16_t*)(ws + (16u << 20));       // [2048][512]   2 MB (over wT)
  bf16_t* vt   = (bf16_t*)(ws + (18u << 20));       // [512][2048]   2 MB (over wT)
  bf16_t* woT  = (bf16_t*)(ws + (20u << 20));       // [2048][2048]  8 MB (over qkvf)
  bf16_t* yb   = (bf16_t*)(ws + (28u << 20));       // [2048][2048]  8 MB (over qkvf)

  const float SCL_Q = 0.18033688011112042f;  // (1/8) * log2(e)

  // 1. x -> bf16
  hipLaunchKernelGGL(cast_f32_bf16_kernel, dim3(2048), dim3(256), 0, stream,
                     x, xb, (T_SEQ * DMODEL) / 8);
  // 2. weight transposes into fused [3072][2048] B^T panel
  hipLaunchKernelGGL(transpose_cast_kernel, dim3(64, 64), dim3(256), 0, stream,
                     wq, wT, DMODEL, NQD, NQD, DMODEL);
  hipLaunchKernelGGL(transpose_cast_kernel, dim3(16, 64), dim3(256), 0, stream,
                     wk, wT + (size_t)NQD * DMODEL, DMODEL, NKVD, NKVD, DMODEL);
  hipLaunchKernelGGL(transpose_cast_kernel, dim3(16, 64), dim3(256), 0, stream,
                     wv, wT + (size_t)(NQD + NKVD) * DMODEL, DMODEL, NKVD, NKVD, DMODEL);
  // 3. fused QKV projection: qkvf = x @ [wq|wk|wv]
  hipLaunchKernelGGL(gemm_bt64_kernel, dim3(QKVN / 64, T_SEQ / 128), dim3(256), 0, stream,
                     xb, wT, qkvf, T_SEQ, QKVN, DMODEL);
  // 4. RoPE + cast Q (pre-scaled), K
  hipLaunchKernelGGL(rope_cast_kernel, dim3((T_SEQ * NHEADS * 32) / 256), dim3(256), 0, stream,
                     qkvf, fc, qb, NHEADS, QKVN, SCL_Q);
  hipLaunchKernelGGL(rope_cast_kernel, dim3((T_SEQ * NKV * 32) / 256), dim3(256), 0, stream,
                     qkvf + NQD, fc, kb, NKV, QKVN, 1.0f);
  // 5. V -> VT (bf16, [512][2048])
  hipLaunchKernelGGL(transpose_cast_kernel, dim3(16, 64), dim3(256), 0, stream,
                     qkvf + NQD + NKVD, vt, T_SEQ, NKVD, QKVN, T_SEQ);
  // 6. wo -> woT
  hipLaunchKernelGGL(transpose_cast_kernel, dim3(64, 64), dim3(256), 0, stream,
                     wo, woT, NQD, DMODEL, DMODEL, NQD);
  // 7. attention
  hipLaunchKernelGGL(attn_kernel, dim3(T_SEQ / 32, NKV), dim3(256), 0, stream,
                     qb, kb, vt, yb);
  // 8. output projection -> d_out (fp32)
  hipLaunchKernelGGL(gemm_bt64_kernel, dim3(DMODEL / 64, T_SEQ / 128), dim3(256), 0, stream,
                     yb, woT, out, T_SEQ, DMODEL, NQD);
}

// Round 5
// 184.669 us; speedup vs baseline: 2.0820x; 1.0299x over previous
//
#include <hip/hip_runtime.h>
#include <hip/hip_bf16.h>
#include <stdint.h>
#include <stddef.h>

#define T_SEQ 2048
#define DMODEL 2048
#define NHEADS 32
#define NKV 8
#define HD 64
#define NQD (NHEADS * HD)        // 2048
#define NKVD (NKV * HD)          // 512
#define QKVN (NQD + 2 * NKVD)    // 3072

typedef __bf16 bf16_t;
typedef __bf16 bf16x8 __attribute__((ext_vector_type(8)));
typedef __bf16 bf16x4 __attribute__((ext_vector_type(4)));
typedef __bf16 bf16x2 __attribute__((ext_vector_type(2)));
typedef float f32x4 __attribute__((ext_vector_type(4)));

typedef __attribute__((address_space(1))) void gvoid_t;
typedef __attribute__((address_space(3))) void lvoid_t;

__device__ __forceinline__ void gload_lds16(const void* g, void* l) {
  __builtin_amdgcn_global_load_lds((gvoid_t*)g, (lvoid_t*)l, 16, 0, 0);
}

// ---------------- elementwise cast f32 -> bf16 (8 elems/thread) ----------------
__global__ __launch_bounds__(256) void cast_f32_bf16_kernel(
    const float* __restrict__ in, bf16_t* __restrict__ out, int n8) {
  int i = blockIdx.x * 256 + threadIdx.x;
  if (i >= n8) return;
  const float4* p = (const float4*)in + (size_t)i * 2;
  float4 a = p[0], b = p[1];
  bf16x8 o = {(bf16_t)a.x, (bf16_t)a.y, (bf16_t)a.z, (bf16_t)a.w,
              (bf16_t)b.x, (bf16_t)b.y, (bf16_t)b.z, (bf16_t)b.w};
  *(bf16x8*)(out + (size_t)i * 8) = o;
}

// ---------------- tiled transpose + cast: out[c][r] = (bf16) in[r][c] ----------------
__global__ __launch_bounds__(256) void transpose_cast_kernel(
    const float* __restrict__ in, bf16_t* __restrict__ out,
    int R, int C, int ldin, int ldout) {
  __shared__ float tile[32][33];
  const int c0 = blockIdx.x * 32, r0 = blockIdx.y * 32;
  const int tx = threadIdx.x & 31, ty = threadIdx.x >> 5;
#pragma unroll
  for (int i = 0; i < 32; i += 8)
    tile[ty + i][tx] = in[(size_t)(r0 + ty + i) * ldin + c0 + tx];
  __syncthreads();
#pragma unroll
  for (int i = 0; i < 32; i += 8)
    out[(size_t)(c0 + ty + i) * ldout + r0 + tx] = (bf16_t)tile[tx][ty + i];
}

// ---------------- RoPE + cast (oscale folds attention scale into Q) ----------------
__global__ __launch_bounds__(256) void rope_cast_kernel(
    const float* __restrict__ src, const float* __restrict__ fc,
    bf16_t* __restrict__ dst, int H, int ldin, float oscale) {
  const int i = blockIdx.x * 256 + threadIdx.x;  // global pair index
  const int npr = H * 32;
  const int t = i / npr;
  const int rem = i - t * npr;
  const int h = rem >> 5, fi = rem & 31;
  const float2 rein = *(const float2*)&src[(size_t)t * ldin + h * 64 + fi * 2];
  const float2 cs = *(const float2*)&fc[((size_t)t * 32 + fi) * 2];
  const float o0 = (rein.x * cs.x - rein.y * cs.y) * oscale;
  const float o1 = (rein.x * cs.y + rein.y * cs.x) * oscale;
  bf16x2 ob = {(bf16_t)o0, (bf16_t)o1};
  *(bf16x2*)&dst[(size_t)t * (H * 64) + h * 64 + fi * 2] = ob;
}

// ---------------- GEMM: C(f32, MxN) = A(bf16, MxK) * BT(bf16, NxK)^T ----------------
// 128(M)x64(N) tile, BK=64, 256 threads, XOR-swizzled LDS via global_load_lds.
__global__ __launch_bounds__(256) void gemm_bt64_kernel(
    const bf16_t* __restrict__ A, const bf16_t* __restrict__ BT,
    float* __restrict__ C, int M, int N, int K) {
  __shared__ bf16_t As[128 * 64];  // 16KB
  __shared__ bf16_t Bs[64 * 64];   // 8KB
  const int tid = threadIdx.x;
  const int lane = tid & 63;
  const int w = tid >> 6;
  const int lr = lane & 15, lg = lane >> 4;
  const int m0 = blockIdx.y * 128, n0 = blockIdx.x * 64;
  const int wm = (w >> 1) * 64, wn = (w & 1) * 32;

  const bf16_t* gA[4];
  bf16_t* lA[4];
#pragma unroll
  for (int j = 0; j < 4; ++j) {
    const int c = tid + j * 256;
    const int row = c >> 3, cc = c & 7;
    gA[j] = A + (size_t)(m0 + row) * K + ((cc ^ (row & 7)) * 8);
    lA[j] = As + c * 8;
  }
  const bf16_t* gB[2];
  bf16_t* lB[2];
#pragma unroll
  for (int j = 0; j < 2; ++j) {
    const int c = tid + j * 256;
    const int row = c >> 3, cc = c & 7;
    gB[j] = BT + (size_t)(n0 + row) * K + ((cc ^ (row & 7)) * 8);
    lB[j] = Bs + c * 8;
  }

  f32x4 acc[4][2] = {};

  for (int k0 = 0; k0 < K; k0 += 64) {
#pragma unroll
    for (int j = 0; j < 4; ++j) gload_lds16(gA[j] + k0, lA[j]);
#pragma unroll
    for (int j = 0; j < 2; ++j) gload_lds16(gB[j] + k0, lB[j]);
    __syncthreads();
#pragma unroll
    for (int ks = 0; ks < 2; ++ks) {
      bf16x8 af[4], bfr[2];
#pragma unroll
      for (int mi = 0; mi < 4; ++mi) {
        const int row = wm + mi * 16 + lr;
        af[mi] = *(const bf16x8*)((const char*)As + row * 128 +
                                  ((ks * 64 + lg * 16) ^ ((row & 7) << 4)));
      }
#pragma unroll
      for (int nj = 0; nj < 2; ++nj) {
        const int row = wn + nj * 16 + lr;
        bfr[nj] = *(const bf16x8*)((const char*)Bs + row * 128 +
                                   ((ks * 64 + lg * 16) ^ ((row & 7) << 4)));
      }
      __builtin_amdgcn_s_setprio(1);
#pragma unroll
      for (int mi = 0; mi < 4; ++mi)
#pragma unroll
        for (int nj = 0; nj < 2; ++nj)
          acc[mi][nj] = __builtin_amdgcn_mfma_f32_16x16x32_bf16(
              af[mi], bfr[nj], acc[mi][nj], 0, 0, 0);
      __builtin_amdgcn_s_setprio(0);
    }
    __syncthreads();
  }

#pragma unroll
  for (int mi = 0; mi < 4; ++mi)
#pragma unroll
    for (int nj = 0; nj < 2; ++nj) {
      const int row = m0 + wm + mi * 16 + lg * 4;
      const int col = n0 + wn + nj * 16 + lr;
#pragma unroll
      for (int r = 0; r < 4; ++r)
        C[(size_t)(row + r) * N + col] = acc[mi][nj][r];
    }
}

// ---------------- causal GQA flash attention v5 (s-split) ----------------
// Work items per kv-head: 96. idx<32: (qt=idx, whole range). idx>=32:
// qt=32+(idx-32)/2, chunk c=(idx-32)&1; c0 = s-tiles [0,16), c1 = [16,nt).
// grid = 768 blocks (heavy-first, kh-interleaved: kh=bid&7, idx=95-(bid>>3)).
// Single-chunk blocks write yb directly; split blocks write normalized bf16
// partials + (m,l) merged by merge_kernel.
__global__ __launch_bounds__(256) void attn_kernel(
    const bf16_t* __restrict__ Q, const bf16_t* __restrict__ Kb,
    const bf16_t* __restrict__ VT, bf16_t* __restrict__ Y,
    bf16_t* __restrict__ Yp, float* __restrict__ Mb, float* __restrict__ Lb) {
  __shared__ bf16_t Ks[2][64 * 64];
  __shared__ bf16_t Vs[2][64 * 64];
  __shared__ char Pb[4][32 * 128];
  const int bid = blockIdx.x;
  const int kh = bid & 7;
  const int idx = 95 - (bid >> 3);
  int qt, c;
  if (idx < 32) { qt = idx; c = 0; }
  else { const int t2 = idx - 32; qt = 32 + (t2 >> 1); c = t2 & 1; }
  const int nt = (qt + 2) >> 1;
  const bool single = (nt <= 16);
  const int tstart = c * 16;
  const int tend = (c == 0) ? (single ? nt : 16) : nt;

  const int tid = threadIdx.x, lane = tid & 63, w = tid >> 6;
  const int h = kh * 4 + w;
  const int lr = lane & 15, lg = lane >> 4;
  const int q0 = qt * 32;
  char* pb = (char*)Pb[w];
  const int swz = (lr & 7) << 4;

  // staging: wave w stages rows [w*8,+8) and [(w+4)*8,+8) of K and V^T tiles.
  const int rA = w * 8 + (lane >> 3);
  const int rB = (w + 4) * 8 + (lane >> 3);
  const int ce = (((lane & 7) ^ (lane >> 3)) * 8);  // pre-swizzled col chunk
  const bf16_t* kgA = Kb + (size_t)rA * NKVD + kh * HD + ce;
  const bf16_t* kgB = Kb + (size_t)rB * NKVD + kh * HD + ce;
  const bf16_t* vgA = VT + (size_t)(kh * HD + rA) * T_SEQ + ce;
  const bf16_t* vgB = VT + (size_t)(kh * HD + rB) * T_SEQ + ce;
  const int ldA = w * 512 + lane * 8;
  const int ldB = (w + 4) * 512 + lane * 8;

  // Q fragments (B operand of swapped QK^T)
  bf16x8 qf[2][2];
#pragma unroll
  for (int iq = 0; iq < 2; ++iq)
#pragma unroll
    for (int ks = 0; ks < 2; ++ks)
      qf[iq][ks] = *(const bf16x8*)&Q[(size_t)(q0 + iq * 16 + lr) * NQD + h * HD + ks * 32 + lg * 8];

  float m_i[2] = {-1e30f, -1e30f}, l_i[2] = {0.f, 0.f};  // lane-partial l
  f32x4 acc_o[2][4] = {};

  // prologue: stage tile tstart into buffer 0
  {
    const size_t ko = (size_t)tstart * 64 * NKVD;
    gload_lds16(kgA + ko, &Ks[0][ldA]);
    gload_lds16(kgB + ko, &Ks[0][ldB]);
    gload_lds16(vgA + tstart * 64, &Vs[0][ldA]);
    gload_lds16(vgB + tstart * 64, &Vs[0][ldB]);
  }
  __syncthreads();

  int cur = 0;
  for (int t = tstart; t < tend; ++t) {
    const int s0 = t * 64;
    if (t + 1 < tend) {
      const size_t ko = (size_t)(s0 + 64) * NKVD;
      gload_lds16(kgA + ko, &Ks[cur ^ 1][ldA]);
      gload_lds16(kgB + ko, &Ks[cur ^ 1][ldB]);
      gload_lds16(vgA + s0 + 64, &Vs[cur ^ 1][ldA]);
      gload_lds16(vgB + s0 + 64, &Vs[cur ^ 1][ldB]);
    }
    const char* kbase = (const char*)&Ks[cur][0];
    const char* vbase = (const char*)&Vs[cur][0];

    bf16x8 kf[4][2];
#pragma unroll
    for (int j = 0; j < 4; ++j)
#pragma unroll
      for (int ks = 0; ks < 2; ++ks)
        kf[j][ks] = *(const bf16x8*)(kbase + (j * 16 + lr) * 128 + ((ks * 64 + lg * 16) ^ swz));

    // S^T = K·Q^T (exp2 domain: Q pre-scaled by 0.125*log2e)
    f32x4 st[2][4] = {};
    __builtin_amdgcn_s_setprio(1);
#pragma unroll
    for (int iq = 0; iq < 2; ++iq)
#pragma unroll
      for (int j = 0; j < 4; ++j)
#pragma unroll
        for (int ks = 0; ks < 2; ++ks)
          st[iq][j] = __builtin_amdgcn_mfma_f32_16x16x32_bf16(kf[j][ks], qf[iq][ks], st[iq][j], 0, 0, 0);
    __builtin_amdgcn_s_setprio(0);

    // V fragments hoisted (independent of softmax)
    bf16x8 vf[2][4];
#pragma unroll
    for (int ks = 0; ks < 2; ++ks)
#pragma unroll
      for (int df = 0; df < 4; ++df)
        vf[ks][df] = *(const bf16x8*)(vbase + (df * 16 + lr) * 128 + ((ks * 64 + lg * 16) ^ swz));

    const bool domask = (s0 + 64 > q0);  // block-uniform
#pragma unroll
    for (int iq = 0; iq < 2; ++iq) {
      float sv[16];
      const int tq = q0 + iq * 16 + lr;
#pragma unroll
      for (int j = 0; j < 4; ++j)
#pragma unroll
        for (int r = 0; r < 4; ++r) {
          float v = st[iq][j][r];
          if (domask && (s0 + j * 16 + lg * 4 + r > tq)) v = -1e30f;
          sv[j * 4 + r] = v;
        }
      float pm = fmaxf(fmaxf(fmaxf(sv[0], sv[1]), fmaxf(sv[2], sv[3])),
                       fmaxf(fmaxf(sv[4], sv[5]), fmaxf(sv[6], sv[7])));
      float pm2 = fmaxf(fmaxf(fmaxf(sv[8], sv[9]), fmaxf(sv[10], sv[11])),
                        fmaxf(fmaxf(sv[12], sv[13]), fmaxf(sv[14], sv[15])));
      pm = fmaxf(pm, pm2);
      pm = fmaxf(pm, __shfl_xor(pm, 16));
      pm = fmaxf(pm, __shfl_xor(pm, 32));

      if (!__all(pm <= m_i[iq] + 8.0f)) {  // defer-max
        const float mnew = fmaxf(m_i[iq], pm);
        const float es = exp2f(m_i[iq] - mnew);
        m_i[iq] = mnew;
        l_i[iq] *= es;
        float eso[4];
#pragma unroll
        for (int r = 0; r < 4; ++r) eso[r] = __shfl(es, lg * 4 + r);
#pragma unroll
        for (int df = 0; df < 4; ++df)
#pragma unroll
          for (int r = 0; r < 4; ++r) acc_o[iq][df][r] *= eso[r];
      }

      float rs0 = 0.f, rs1 = 0.f;
      bf16_t pe[16];
#pragma unroll
      for (int z = 0; z < 8; ++z) {
        const float p = exp2f(sv[z] - m_i[iq]);
        rs0 += p;
        pe[z] = (bf16_t)p;
      }
#pragma unroll
      for (int z = 8; z < 16; ++z) {
        const float p = exp2f(sv[z] - m_i[iq]);
        rs1 += p;
        pe[z] = (bf16_t)p;
      }
      l_i[iq] += rs0 + rs1;

#pragma unroll
      for (int j = 0; j < 4; ++j) {
        bf16x4 pk = {pe[j * 4 + 0], pe[j * 4 + 1], pe[j * 4 + 2], pe[j * 4 + 3]};
        *(bf16x4*)(pb + (iq * 16 + lr) * 128 + ((j * 32 + lg * 8) ^ swz)) = pk;
      }
    }

    bf16x8 pa[2][2];
#pragma unroll
    for (int iq = 0; iq < 2; ++iq)
#pragma unroll
      for (int ks = 0; ks < 2; ++ks)
        pa[iq][ks] = *(const bf16x8*)(pb + (iq * 16 + lr) * 128 + ((ks * 64 + lg * 16) ^ swz));

    __builtin_amdgcn_s_setprio(1);
#pragma unroll
    for (int iq = 0; iq < 2; ++iq)
#pragma unroll
      for (int df = 0; df < 4; ++df)
#pragma unroll
        for (int ks = 0; ks < 2; ++ks)
          acc_o[iq][df] = __builtin_amdgcn_mfma_f32_16x16x32_bf16(pa[iq][ks], vf[ks][df], acc_o[iq][df], 0, 0, 0);
    __builtin_amdgcn_s_setprio(0);

    __syncthreads();
    cur ^= 1;
  }

  // epilogue: reduce l, normalize, write
  float lts[2];
#pragma unroll
  for (int iq = 0; iq < 2; ++iq) {
    float lt = l_i[iq];
    lt += __shfl_xor(lt, 16);
    lt += __shfl_xor(lt, 32);
    lts[iq] = lt;
  }
  if (single) {
#pragma unroll
    for (int iq = 0; iq < 2; ++iq) {
      float lf[4];
#pragma unroll
      for (int r = 0; r < 4; ++r) lf[r] = __shfl(lts[iq], lg * 4 + r);
#pragma unroll
      for (int r = 0; r < 4; ++r) {
        const float inv = 1.f / lf[r];
        const int t = q0 + iq * 16 + lg * 4 + r;
#pragma unroll
        for (int df = 0; df < 4; ++df)
          Y[(size_t)t * NQD + h * HD + df * 16 + lr] = (bf16_t)(acc_o[iq][df][r] * inv);
      }
    }
  } else {
    const int cid = (kh * 32 + (qt - 32)) * 2 + c;
    bf16_t* yp = Yp + ((size_t)cid * 4 + w) * 2048;  // [32 q][64 d]
#pragma unroll
    for (int iq = 0; iq < 2; ++iq) {
      float lf[4];
#pragma unroll
      for (int r = 0; r < 4; ++r) lf[r] = __shfl(lts[iq], lg * 4 + r);
#pragma unroll
      for (int r = 0; r < 4; ++r) {
        const float inv = 1.f / lf[r];
        const int q = iq * 16 + lg * 4 + r;
#pragma unroll
        for (int df = 0; df < 4; ++df)
          yp[q * 64 + df * 16 + lr] = (bf16_t)(acc_o[iq][df][r] * inv);
      }
    }
    if (lg == 0) {
#pragma unroll
      for (int iq = 0; iq < 2; ++iq) {
        Mb[cid * 128 + w * 32 + iq * 16 + lr] = m_i[iq];
        Lb[cid * 128 + w * 32 + iq * 16 + lr] = lts[iq];
      }
    }
  }
}

// ---------------- merge split-s partials ----------------
// grid (32, 8) for qt in [32,64); block 256 = 4 heads x 64 lanes (lane = d).
__global__ __launch_bounds__(256) void merge_kernel(
    const bf16_t* __restrict__ Yp, const float* __restrict__ Mb,
    const float* __restrict__ Lb, bf16_t* __restrict__ Y) {
  const int qt = 32 + blockIdx.x, kh = blockIdx.y;
  const int w = threadIdx.x >> 6, lane = threadIdx.x & 63;
  const int h = kh * 4 + w;
  const int cid0 = (kh * 32 + (qt - 32)) * 2, cid1 = cid0 + 1;
  const bf16_t* y0 = Yp + ((size_t)cid0 * 4 + w) * 2048;
  const bf16_t* y1 = Yp + ((size_t)cid1 * 4 + w) * 2048;
#pragma unroll 4
  for (int q = 0; q < 32; ++q) {
    const float m0 = Mb[cid0 * 128 + w * 32 + q];
    const float m1 = Mb[cid1 * 128 + w * 32 + q];
    const float l0 = Lb[cid0 * 128 + w * 32 + q];
    const float l1 = Lb[cid1 * 128 + w * 32 + q];
    const float M = fmaxf(m0, m1);
    const float a0 = exp2f(m0 - M) * l0;
    const float a1 = exp2f(m1 - M) * l1;
    const float inv = 1.f / (a0 + a1);
    const float v0 = (float)y0[q * 64 + lane];
    const float v1 = (float)y1[q * 64 + lane];
    Y[(size_t)(qt * 32 + q) * NQD + h * HD + lane] = (bf16_t)((v0 * a0 + v1 * a1) * inv);
  }
}

extern "C" void kernel_launch(void* const* d_in, const int* in_sizes, int n_in,
                              void* d_out, int out_size, void* d_ws, size_t ws_size,
                              hipStream_t stream) {
  const float* x = (const float*)d_in[0];
  const float* fc = (const float*)d_in[1];
  const float* wq = (const float*)d_in[2];
  const float* wk = (const float*)d_in[3];
  const float* wv = (const float*)d_in[4];
  const float* wo = (const float*)d_in[5];
  float* out = (float*)d_out;
  char* ws = (char*)d_ws;

  // workspace arena (44 MB), aliased by lifetime:
  bf16_t* xb   = (bf16_t*)(ws + 0);                 // [2048][2048]  8 MB (dead after QKV gemm)
  bf16_t* wT   = (bf16_t*)(ws + (8u << 20));        // [3072][2048] 12 MB (dead after QKV gemm)
  float*  qkvf = (float*)(ws + (20u << 20));        // [2048][3072] 24 MB fp32 (20..44; dead after step 5)
  bf16_t* qb   = (bf16_t*)(ws + (8u << 20));        // [2048][2048]  8 MB (over wT)
  bf16_t* kb   = (bf16_t*)(ws + (16u << 20));       // [2048][512]   2 MB (over wT)
  bf16_t* vt   = (bf16_t*)(ws + (18u << 20));       // [512][2048]   2 MB (over wT)
  bf16_t* woT  = (bf16_t*)(ws + (20u << 20));       // [2048][2048]  8 MB (over qkvf head)
  bf16_t* yb   = (bf16_t*)(ws + 0);                 // [2048][2048]  8 MB (over xb)
  bf16_t* Yp   = (bf16_t*)(ws + (28u << 20));       // 512 chunks x 16KB = 8 MB (over qkvf)
  float*  Mb   = (float*)(ws + (36u << 20));        // 512 x 128 f32 = 256 KB
  float*  Lb   = (float*)(ws + (36u << 20) + (256u << 10));  // 256 KB

  const float SCL_Q = 0.18033688011112042f;  // (1/8) * log2(e)

  // 1. x -> bf16
  hipLaunchKernelGGL(cast_f32_bf16_kernel, dim3(2048), dim3(256), 0, stream,
                     x, xb, (T_SEQ * DMODEL) / 8);
  // 2. weight transposes into fused [3072][2048] B^T panel
  hipLaunchKernelGGL(transpose_cast_kernel, dim3(64, 64), dim3(256), 0, stream,
                     wq, wT, DMODEL, NQD, NQD, DMODEL);
  hipLaunchKernelGGL(transpose_cast_kernel, dim3(16, 64), dim3(256), 0, stream,
                     wk, wT + (size_t)NQD * DMODEL, DMODEL, NKVD, NKVD, DMODEL);
  hipLaunchKernelGGL(transpose_cast_kernel, dim3(16, 64), dim3(256), 0, stream,
                     wv, wT + (size_t)(NQD + NKVD) * DMODEL, DMODEL, NKVD, NKVD, DMODEL);
  // 3. fused QKV projection: qkvf = x @ [wq|wk|wv]
  hipLaunchKernelGGL(gemm_bt64_kernel, dim3(QKVN / 64, T_SEQ / 128), dim3(256), 0, stream,
                     xb, wT, qkvf, T_SEQ, QKVN, DMODEL);
  // 4. RoPE + cast Q (pre-scaled), K
  hipLaunchKernelGGL(rope_cast_kernel, dim3((T_SEQ * NHEADS * 32) / 256), dim3(256), 0, stream,
                     qkvf, fc, qb, NHEADS, QKVN, SCL_Q);
  hipLaunchKernelGGL(rope_cast_kernel, dim3((T_SEQ * NKV * 32) / 256), dim3(256), 0, stream,
                     qkvf + NQD, fc, kb, NKV, QKVN, 1.0f);
  // 5. V -> VT (bf16, [512][2048])
  hipLaunchKernelGGL(transpose_cast_kernel, dim3(16, 64), dim3(256), 0, stream,
                     qkvf + NQD + NKVD, vt, T_SEQ, NKVD, QKVN, T_SEQ);
  // 6. wo -> woT
  hipLaunchKernelGGL(transpose_cast_kernel, dim3(64, 64), dim3(256), 0, stream,
                     wo, woT, NQD, DMODEL, DMODEL, NQD);
  // 7. attention (s-split) + merge
  hipLaunchKernelGGL(attn_kernel, dim3(768), dim3(256), 0, stream,
                     qb, kb, vt, yb, Yp, Mb, Lb);
  hipLaunchKernelGGL(merge_kernel, dim3(32, 8), dim3(256), 0, stream,
                     Yp, Mb, Lb, yb);
  // 8. output projection -> d_out (fp32)
  hipLaunchKernelGGL(gemm_bt64_kernel, dim3(DMODEL / 64, T_SEQ / 128), dim3(256), 0, stream,
                     yb, woT, out, T_SEQ, DMODEL, NQD);
}